// Round 3
// baseline (270.000 us; speedup 1.0000x reference)
//
#include <hip/hip_runtime.h>
#include <hip/hip_bf16.h>

#define DM    1024
#define NH    16
#define DKH   64
#define BB    4
#define SS    2048
#define MROWS (BB*SS)     // 8192
#define NQK   2048        // Q,K fused projection width

typedef __attribute__((ext_vector_type(8))) __bf16 bf16x8;
typedef __attribute__((ext_vector_type(4))) float f32x4;
typedef __attribute__((ext_vector_type(16))) float f32x16;
typedef __attribute__((ext_vector_type(4))) unsigned short u16x4;

__device__ __forceinline__ void gload_lds16(const void* g, void* l) {
  __builtin_amdgcn_global_load_lds((const __attribute__((address_space(1))) void*)g,
                                   (__attribute__((address_space(3))) void*)l, 16, 0, 0);
}

__device__ __forceinline__ unsigned short f2bf(float f) {
  __hip_bfloat16 h = __float2bfloat16(f);
  unsigned short u;
  __builtin_memcpy(&u, &h, 2);
  return u;
}

__device__ __forceinline__ unsigned pack2(float a, float b) {
  return (unsigned)f2bf(a) | ((unsigned)f2bf(b) << 16);
}

// ---------------- conversion kernels ----------------

__global__ __launch_bounds__(256) void cvt_bf16_kernel(const float* __restrict__ in,
                                                       unsigned short* __restrict__ out, int n4) {
  int i = blockIdx.x * 256 + threadIdx.x;
  if (i >= n4) return;
  float4 v = reinterpret_cast<const float4*>(in)[i];
  u16x4 o = { f2bf(v.x), f2bf(v.y), f2bf(v.z), f2bf(v.w) };
  reinterpret_cast<u16x4*>(out)[i] = o;
}

__global__ __launch_bounds__(256) void transpose_cvt_kernel(const float* __restrict__ W,
                                                            unsigned short* __restrict__ WT) {
  __shared__ float t[32][33];
  int tx = threadIdx.x & 31, ty = threadIdx.x >> 5;
  int bx = blockIdx.x * 32, by = blockIdx.y * 32;
#pragma unroll
  for (int i = 0; i < 32; i += 8)
    t[ty + i][tx] = W[(long)(by + ty + i) * DM + bx + tx];
  __syncthreads();
#pragma unroll
  for (int i = 0; i < 32; i += 8)
    WT[(long)(bx + ty + i) * DM + by + tx] = f2bf(t[tx][ty + i]);
}

__global__ void concat2_bias_kernel(const float* __restrict__ a, const float* __restrict__ b,
                                    float* __restrict__ out) {
  int i = blockIdx.x * 256 + threadIdx.x;
  if (i >= NQK) return;
  out[i] = (i < DM) ? a[i] : b[i - DM];
}

// ---------------- GEMM: C[M][N] = A[M][K] * BT[N][K]^T + bias (m97 structure) ----------------

__device__ __forceinline__ void store_out(float* p, float v) { *p = v; }
__device__ __forceinline__ void store_out(unsigned short* p, float v) { *p = f2bf(v); }

template <typename OutT, bool Q_SCALE, bool BIAS_ROW>
__global__ __launch_bounds__(256) void gemm_bt_kernel(
    const unsigned short* __restrict__ A,   // [M][K] bf16 bits
    const unsigned short* __restrict__ BT,  // [N][K] bf16 bits
    const float* __restrict__ bias,         // [N] (or [M] if BIAS_ROW)
    OutT* __restrict__ C, int M, int N, int K) {
  __shared__ unsigned short As[128 * 32];
  __shared__ unsigned short Bs[128 * 32];
  const int tid = threadIdx.x;
  const int lane = tid & 63;
  const int lr = lane & 15, lg = lane >> 4;
  const int wv = tid >> 6, wm = wv >> 1, wn = wv & 1;
  const long bm = blockIdx.x, bn = blockIdx.y;

  const unsigned short* Ag = A + bm * 128 * K;
  const unsigned short* Bg = BT + bn * 128 * K;

  f32x4 acc[4][4];
#pragma unroll
  for (int i = 0; i < 4; ++i)
#pragma unroll
    for (int j = 0; j < 4; ++j) acc[i][j] = (f32x4){0.f, 0.f, 0.f, 0.f};

  for (int kt = 0; kt < K; kt += 32) {
#pragma unroll
    for (int it = 0; it < 2; ++it) {
      const int e = it * 2048 + tid * 8;
      const int row = e >> 5, col = e & 31;
      gload_lds16(Ag + (long)row * K + kt + col, As + e);
      gload_lds16(Bg + (long)row * K + kt + col, Bs + e);
    }
    __syncthreads();
    bf16x8 af[4], bfr[4];
#pragma unroll
    for (int mi = 0; mi < 4; ++mi)
      af[mi] = *reinterpret_cast<const bf16x8*>(As + (wm * 64 + mi * 16 + lr) * 32 + lg * 8);
#pragma unroll
    for (int ni = 0; ni < 4; ++ni)
      bfr[ni] = *reinterpret_cast<const bf16x8*>(Bs + (wn * 64 + ni * 16 + lr) * 32 + lg * 8);
#pragma unroll
    for (int mi = 0; mi < 4; ++mi)
#pragma unroll
      for (int ni = 0; ni < 4; ++ni)
        acc[mi][ni] = __builtin_amdgcn_mfma_f32_16x16x32_bf16(af[mi], bfr[ni], acc[mi][ni], 0, 0, 0);
    __syncthreads();
  }

#pragma unroll
  for (int ni = 0; ni < 4; ++ni) {
    const int col = (int)bn * 128 + wn * 64 + ni * 16 + lr;
    const float bc = BIAS_ROW ? 0.f : bias[col];
    // fold softmax scale (1/sqrt(dk)) * log2(e) into Q so attention uses exp2 natively
    const float sc = (Q_SCALE && col < DM) ? (0.125f * 1.44269504088896340736f) : 1.0f;
#pragma unroll
    for (int mi = 0; mi < 4; ++mi) {
      const long row0 = bm * 128 + wm * 64 + mi * 16 + lg * 4;
#pragma unroll
      for (int r = 0; r < 4; ++r) {
        const float bv = BIAS_ROW ? bias[row0 + r] : bc;
        float v = (acc[mi][ni][r] + bv) * sc;
        store_out(&C[(row0 + r) * (long)N + col], v);
      }
    }
  }
}

// ---------------- flash attention v3: 32x32 MFMA + cross-half P exchange ----------------
// block = (b,h) x 128 q-rows; 4 waves x 32 q (one 32-col B operand each).
// QK^T swapped at 32x32x16: S[key][q], q = lane&31 -> scalar m/l per lane, 1 shuffle per reduce.
// P redistribution for PV B-operand = lane<->lane+32 word exchange (shfl_xor 32 + select). No P LDS.
// K staged as [dblk8][key64] 16B-units, V^T as [keyblk8][d64]: ds_read_b128 reads are contiguous
// 512B runs -> zero bank conflicts, and global_load_lds destinations stay linear (no swizzle).

__global__ __launch_bounds__(256) void attn_kernel(
    const unsigned short* __restrict__ QK,   // [8192][2048] bf16: cols 0..1023 Q (prescaled), 1024.. K
    const unsigned short* __restrict__ Vt,   // [1024][8192] bf16: row h*64+d, col b*2048+s
    unsigned short* __restrict__ AO) {       // [8192][1024] bf16 [b][s][h][dk]
  __shared__ __align__(16) unsigned char smem[32768];
  unsigned short* KsB = (unsigned short*)smem;            // 2 bufs x 4096 ushort (8KB each)
  unsigned short* VsB = (unsigned short*)(smem + 16384);

  const int tid = threadIdx.x;
  const int lane = tid & 63;
  const int wv = tid >> 6;
  const int q5 = lane & 31;   // this lane's q column
  const int hi = lane >> 5;   // k-half / key-half selector

  const int bh = blockIdx.x;  // x = bh so all q-tiles of one (b,h) share an XCD
  const int qt = blockIdx.y;
  const int b = bh >> 4, h = bh & 15;

  const unsigned short* Qp = QK + (long)b * SS * NQK + h * DKH;
  const unsigned short* Kp = Qp + DM;
  const unsigned short* Vp = Vt + (long)h * DKH * MROWS + (long)b * SS;

  // Q (B-operand): col = q5, k = dstep*16 + hi*8 + i
  bf16x8 qf[4];
  {
    const unsigned short* qrow = Qp + (long)(qt * 128 + wv * 32 + q5) * NQK;
#pragma unroll
    for (int dstep = 0; dstep < 4; ++dstep)
      qf[dstep] = *reinterpret_cast<const bf16x8*>(qrow + dstep * 16 + hi * 8);
  }

  f32x16 accv[2];  // O^T: col q = q5, row d = dblk*32 + (r&3) + 8*(r>>2) + 4*hi
#pragma unroll
  for (int d = 0; d < 2; ++d)
#pragma unroll
    for (int r = 0; r < 16; ++r) accv[d][r] = 0.f;
  float m_run = -1e30f, l_run = 0.f;

  auto stage = [&](int buf, int t) {
    unsigned short* kd = KsB + buf * 4096;
    unsigned short* vd = VsB + buf * 4096;
#pragma unroll
    for (int it = 0; it < 2; ++it) {
      const int u = it * 256 + tid;  // 16B-unit index 0..511
      // K unit (dblk = u>>6, key = u&63) <- K[key][dblk*8..+7]
      gload_lds16(Kp + (long)(t * 64 + (u & 63)) * NQK + (u >> 6) * 8, kd + u * 8);
      // V unit (keyblk = u>>6, d = u&63) <- V^T[d][keyblk*8..+7]
      gload_lds16(Vp + (long)(u & 63) * MROWS + t * 64 + (u >> 6) * 8, vd + u * 8);
    }
  };

  stage(0, 0);
  __syncthreads();

  const int NT = SS / 64;
  for (int kt = 0; kt < NT; ++kt) {
    const int cur = kt & 1;
    if (kt + 1 < NT) stage(cur ^ 1, kt + 1);  // prefetch hides under compute
    const unsigned short* K_ = KsB + cur * 4096;
    const unsigned short* V_ = VsB + cur * 4096;

    // ---- QK^T (swapped, 32x32x16): s4[kb] = S[key = kb*32 + rowmap][q5] ----
    f32x16 s4[2];
#pragma unroll
    for (int kb = 0; kb < 2; ++kb)
#pragma unroll
      for (int r = 0; r < 16; ++r) s4[kb][r] = 0.f;
    __builtin_amdgcn_s_setprio(1);
#pragma unroll
    for (int kb = 0; kb < 2; ++kb)
#pragma unroll
      for (int dstep = 0; dstep < 4; ++dstep) {
        bf16x8 kf = *reinterpret_cast<const bf16x8*>(
            K_ + ((dstep * 2 + hi) * 64 + kb * 32 + q5) * 8);
        s4[kb] = __builtin_amdgcn_mfma_f32_32x32x16_bf16(kf, qf[dstep], s4[kb], 0, 0, 0);
      }
    __builtin_amdgcn_s_setprio(0);

    // ---- tile max (tree) + single cross-half shuffle ----
    float tmax[16];
#pragma unroll
    for (int r = 0; r < 16; ++r) tmax[r] = fmaxf(s4[0][r], s4[1][r]);
#pragma unroll
    for (int w = 8; w >= 1; w >>= 1)
#pragma unroll
      for (int r = 0; r < w; ++r) tmax[r] = fmaxf(tmax[r], tmax[r + w]);
    const float mloc = fmaxf(tmax[0], __shfl_xor(tmax[0], 32));

    // ---- defer-max (T13): rescale only when max grew by > 8 (log2 domain) ----
    if (!__all(mloc <= m_run + 8.0f)) {
      const float mn = fmaxf(m_run, mloc);
      const float scl = __builtin_amdgcn_exp2f(m_run - mn);
      m_run = mn;
      l_run *= scl;
#pragma unroll
      for (int d = 0; d < 2; ++d)
#pragma unroll
        for (int r = 0; r < 16; ++r) accv[d][r] *= scl;
    }

    // ---- exp + sum (tree) ----
#pragma unroll
    for (int kb = 0; kb < 2; ++kb)
#pragma unroll
      for (int r = 0; r < 16; ++r)
        s4[kb][r] = __builtin_amdgcn_exp2f(s4[kb][r] - m_run);
    float tsum[16];
#pragma unroll
    for (int r = 0; r < 16; ++r) tsum[r] = s4[0][r] + s4[1][r];
#pragma unroll
    for (int w = 8; w >= 1; w >>= 1)
#pragma unroll
      for (int r = 0; r < w; ++r) tsum[r] += tsum[r + w];
    l_run += tsum[0] + __shfl_xor(tsum[0], 32);

    // ---- pack P to bf16 pairs, cross-half exchange, PV ----
    // per 16-key step: own words w0..w3 = key-pairs; B-frag needs keys hi*8..hi*8+7:
    //   lo lanes: {w0, w1, partner w0, partner w1}; hi lanes: {partner w2, partner w3, w2, w3}
#pragma unroll
    for (int step = 0; step < 4; ++step) {
      const int kb = step >> 1, rb = (step & 1) * 8;
      const unsigned w0 = pack2(s4[kb][rb + 0], s4[kb][rb + 1]);
      const unsigned w1 = pack2(s4[kb][rb + 2], s4[kb][rb + 3]);
      const unsigned w2 = pack2(s4[kb][rb + 4], s4[kb][rb + 5]);
      const unsigned w3 = pack2(s4[kb][rb + 6], s4[kb][rb + 7]);
      const unsigned x0 = (unsigned)__shfl_xor((int)w0, 32);
      const unsigned x1 = (unsigned)__shfl_xor((int)w1, 32);
      const unsigned x2 = (unsigned)__shfl_xor((int)w2, 32);
      const unsigned x3 = (unsigned)__shfl_xor((int)w3, 32);
      union { unsigned u[4]; bf16x8 v; } pf;
      pf.u[0] = hi ? x2 : w0;
      pf.u[1] = hi ? x3 : w1;
      pf.u[2] = hi ? w2 : x0;
      pf.u[3] = hi ? w3 : x1;
      __builtin_amdgcn_s_setprio(1);
#pragma unroll
      for (int dblk = 0; dblk < 2; ++dblk) {
        bf16x8 vf = *reinterpret_cast<const bf16x8*>(
            V_ + ((step * 2 + hi) * 64 + dblk * 32 + q5) * 8);
        accv[dblk] = __builtin_amdgcn_mfma_f32_32x32x16_bf16(vf, pf.v, accv[dblk], 0, 0, 0);
      }
      __builtin_amdgcn_s_setprio(0);
    }
    __syncthreads();  // drains prefetch vmcnt + guards buffer swap
  }

  // ---- epilogue: normalize, store pairs (d even) as 4B words ----
  const float inv = 1.0f / l_run;
  const long row = (long)b * SS + qt * 128 + wv * 32 + q5;
  unsigned short* orow = AO + row * DM + h * DKH;
#pragma unroll
  for (int dblk = 0; dblk < 2; ++dblk)
#pragma unroll
    for (int j = 0; j < 8; ++j) {
      const int d0 = dblk * 32 + 8 * (j >> 1) + 4 * hi + 2 * (j & 1);
      const unsigned w = pack2(accv[dblk][2 * j] * inv, accv[dblk][2 * j + 1] * inv);
      *reinterpret_cast<unsigned*>(orow + d0) = w;
    }
}

// ---------------- launch ----------------

extern "C" void kernel_launch(void* const* d_in, const int* in_sizes, int n_in,
                              void* d_out, int out_size, void* d_ws, size_t ws_size,
                              hipStream_t stream) {
  const float* x  = (const float*)d_in[0];
  const float* Wq = (const float*)d_in[1];
  const float* bq = (const float*)d_in[2];
  const float* Wk = (const float*)d_in[3];
  const float* bk = (const float*)d_in[4];
  const float* Wv = (const float*)d_in[5];
  const float* bv = (const float*)d_in[6];
  const float* Wo = (const float*)d_in[7];
  const float* bo = (const float*)d_in[8];
  float* out = (float*)d_out;

  char* ws = (char*)d_ws;
  size_t off = 0;
  auto alloc = [&](size_t bytes) {
    void* p = ws + off;
    off += (bytes + 255) & ~(size_t)255;
    return p;
  };
  unsigned short* Xb   = (unsigned short*)alloc((size_t)MROWS * DM * 2);   // x bf16
  unsigned short* WTqk = (unsigned short*)alloc((size_t)2 * DM * DM * 2);  // WqT,WkT stacked [2048][1024]
  unsigned short* WTv  = (unsigned short*)alloc((size_t)DM * DM * 2);      // WvT [1024][1024]
  unsigned short* WTo  = (unsigned short*)alloc((size_t)DM * DM * 2);      // WoT [1024][1024]
  float*          bqk  = (float*)alloc((size_t)NQK * 4);
  unsigned short* QKb  = (unsigned short*)alloc((size_t)MROWS * NQK * 2);  // fused QK output
  unsigned short* Vtb  = (unsigned short*)alloc((size_t)DM * MROWS * 2);   // V^T [1024][8192]
  unsigned short* AOb  = (unsigned short*)alloc((size_t)MROWS * DM * 2);   // attention output

  cvt_bf16_kernel<<<(MROWS * DM / 4 + 255) / 256, 256, 0, stream>>>(x, Xb, MROWS * DM / 4);
  transpose_cvt_kernel<<<dim3(32, 32), 256, 0, stream>>>(Wq, WTqk);
  transpose_cvt_kernel<<<dim3(32, 32), 256, 0, stream>>>(Wk, WTqk + DM * DM);
  transpose_cvt_kernel<<<dim3(32, 32), 256, 0, stream>>>(Wv, WTv);
  transpose_cvt_kernel<<<dim3(32, 32), 256, 0, stream>>>(Wo, WTo);
  concat2_bias_kernel<<<(NQK + 255) / 256, 256, 0, stream>>>(bq, bk, bqk);

  // QK projection: [8192][2048] = Xb @ WTqk^T, Q columns pre-scaled by 0.125*log2(e)
  gemm_bt_kernel<unsigned short, true, false><<<dim3(MROWS / 128, NQK / 128), 256, 0, stream>>>(
      Xb, WTqk, bqk, QKb, MROWS, NQK, DM);
  // V^T directly: Vt[feature][token] = WTv @ Xb^T + bv (bias by row)
  gemm_bt_kernel<unsigned short, false, true><<<dim3(DM / 128, MROWS / 128), 256, 0, stream>>>(
      WTv, Xb, bv, Vtb, DM, MROWS, DM);

  attn_kernel<<<dim3(BB * NH, SS / 128), 256, 0, stream>>>(QKb, Vtb, AOb);

  // output projection -> fp32 d_out
  gemm_bt_kernel<float, false, false><<<dim3(MROWS / 128, DM / 128), 256, 0, stream>>>(
      AOb, WTo, bo, out, MROWS, DM, DM);
}

// Round 4
// 252.982 us; speedup vs baseline: 1.0673x; 1.0673x over previous
//
#include <hip/hip_runtime.h>
#include <hip/hip_bf16.h>

#define DM    1024
#define NH    16
#define DKH   64
#define BB    4
#define SS    2048
#define MROWS (BB*SS)     // 8192
#define NQK   2048        // Q,K fused projection width

typedef __attribute__((ext_vector_type(8))) __bf16 bf16x8;
typedef __attribute__((ext_vector_type(4))) float f32x4;
typedef __attribute__((ext_vector_type(16))) float f32x16;
typedef __attribute__((ext_vector_type(4))) unsigned short u16x4;

__device__ __forceinline__ void gload_lds16(const void* g, void* l) {
  __builtin_amdgcn_global_load_lds((const __attribute__((address_space(1))) void*)g,
                                   (__attribute__((address_space(3))) void*)l, 16, 0, 0);
}

__device__ __forceinline__ unsigned short f2bf(float f) {
  __hip_bfloat16 h = __float2bfloat16(f);
  unsigned short u;
  __builtin_memcpy(&u, &h, 2);
  return u;
}

__device__ __forceinline__ unsigned pack2(float a, float b) {
  return (unsigned)f2bf(a) | ((unsigned)f2bf(b) << 16);
}

// ---------------- conversion kernels ----------------

__global__ __launch_bounds__(256) void cvt_bf16_kernel(const float* __restrict__ in,
                                                       unsigned short* __restrict__ out, int n4) {
  int i = blockIdx.x * 256 + threadIdx.x;
  if (i >= n4) return;
  float4 v = reinterpret_cast<const float4*>(in)[i];
  u16x4 o = { f2bf(v.x), f2bf(v.y), f2bf(v.z), f2bf(v.w) };
  reinterpret_cast<u16x4*>(out)[i] = o;
}

__global__ __launch_bounds__(256) void transpose_cvt_kernel(const float* __restrict__ W,
                                                            unsigned short* __restrict__ WT) {
  __shared__ float t[32][33];
  int tx = threadIdx.x & 31, ty = threadIdx.x >> 5;
  int bx = blockIdx.x * 32, by = blockIdx.y * 32;
#pragma unroll
  for (int i = 0; i < 32; i += 8)
    t[ty + i][tx] = W[(long)(by + ty + i) * DM + bx + tx];
  __syncthreads();
#pragma unroll
  for (int i = 0; i < 32; i += 8)
    WT[(long)(bx + ty + i) * DM + by + tx] = f2bf(t[tx][ty + i]);
}

__global__ void concat2_bias_kernel(const float* __restrict__ a, const float* __restrict__ b,
                                    float* __restrict__ out) {
  int i = blockIdx.x * 256 + threadIdx.x;
  if (i >= NQK) return;
  out[i] = (i < DM) ? a[i] : b[i - DM];
}

// ---------------- GEMM: C[M][N] = A[M][K] * BT[N][K]^T + bias (m97 structure) ----------------

__device__ __forceinline__ void store_out(float* p, float v) { *p = v; }
__device__ __forceinline__ void store_out(unsigned short* p, float v) { *p = f2bf(v); }

template <typename OutT, bool Q_SCALE, bool BIAS_ROW>
__global__ __launch_bounds__(256) void gemm_bt_kernel(
    const unsigned short* __restrict__ A,   // [M][K] bf16 bits
    const unsigned short* __restrict__ BT,  // [N][K] bf16 bits
    const float* __restrict__ bias,         // [N] (or [M] if BIAS_ROW)
    OutT* __restrict__ C, int M, int N, int K) {
  __shared__ unsigned short As[128 * 32];
  __shared__ unsigned short Bs[128 * 32];
  const int tid = threadIdx.x;
  const int lane = tid & 63;
  const int lr = lane & 15, lg = lane >> 4;
  const int wv = tid >> 6, wm = wv >> 1, wn = wv & 1;
  const long bm = blockIdx.x, bn = blockIdx.y;

  const unsigned short* Ag = A + bm * 128 * K;
  const unsigned short* Bg = BT + bn * 128 * K;

  f32x4 acc[4][4];
#pragma unroll
  for (int i = 0; i < 4; ++i)
#pragma unroll
    for (int j = 0; j < 4; ++j) acc[i][j] = (f32x4){0.f, 0.f, 0.f, 0.f};

  for (int kt = 0; kt < K; kt += 32) {
#pragma unroll
    for (int it = 0; it < 2; ++it) {
      const int e = it * 2048 + tid * 8;
      const int row = e >> 5, col = e & 31;
      gload_lds16(Ag + (long)row * K + kt + col, As + e);
      gload_lds16(Bg + (long)row * K + kt + col, Bs + e);
    }
    __syncthreads();
    bf16x8 af[4], bfr[4];
#pragma unroll
    for (int mi = 0; mi < 4; ++mi)
      af[mi] = *reinterpret_cast<const bf16x8*>(As + (wm * 64 + mi * 16 + lr) * 32 + lg * 8);
#pragma unroll
    for (int ni = 0; ni < 4; ++ni)
      bfr[ni] = *reinterpret_cast<const bf16x8*>(Bs + (wn * 64 + ni * 16 + lr) * 32 + lg * 8);
#pragma unroll
    for (int mi = 0; mi < 4; ++mi)
#pragma unroll
      for (int ni = 0; ni < 4; ++ni)
        acc[mi][ni] = __builtin_amdgcn_mfma_f32_16x16x32_bf16(af[mi], bfr[ni], acc[mi][ni], 0, 0, 0);
    __syncthreads();
  }

#pragma unroll
  for (int ni = 0; ni < 4; ++ni) {
    const int col = (int)bn * 128 + wn * 64 + ni * 16 + lr;
    const float bc = BIAS_ROW ? 0.f : bias[col];
    // fold softmax scale (1/sqrt(dk)) * log2(e) into Q so attention uses exp2 natively
    const float sc = (Q_SCALE && col < DM) ? (0.125f * 1.44269504088896340736f) : 1.0f;
#pragma unroll
    for (int mi = 0; mi < 4; ++mi) {
      const long row0 = bm * 128 + wm * 64 + mi * 16 + lg * 4;
#pragma unroll
      for (int r = 0; r < 4; ++r) {
        const float bv = BIAS_ROW ? bias[row0 + r] : bc;
        float v = (acc[mi][ni][r] + bv) * sc;
        store_out(&C[(row0 + r) * (long)N + col], v);
      }
    }
  }
}

// ---------------- flash attention v4: cross-tile software pipeline (T15) ----------------
// block = (b,h) x 128 q-rows; 4 waves x 32 q (one 32-col B operand each).
// Iteration i: issue stage K(i+1), V(i); QK(i) -> fresh s4 (zero-C, no cross-tile dep);
// softmax+PV of tile i-1 from the OTHER s4 buffer. QK(i) MFMAs and softmax(i-1) VALU are
// register-disjoint -> scheduler interleaves, hiding both latencies within one wave.
// V staged one tile late => K,V each double-buffered (32 KB total). Zero-conflict layouts
// as v3: K [dblk8][key64] 16B-units, V^T [keyblk8][d64].

__global__ __launch_bounds__(256, 3) void attn_kernel(
    const unsigned short* __restrict__ QK,   // [8192][2048] bf16: cols 0..1023 Q (prescaled), 1024.. K
    const unsigned short* __restrict__ Vt,   // [1024][8192] bf16: row h*64+d, col b*2048+s
    unsigned short* __restrict__ AO) {       // [8192][1024] bf16 [b][s][h][dk]
  __shared__ __align__(16) unsigned char smem[32768];
  unsigned short* K0 = (unsigned short*)smem;            // 4096 ushort each (8KB)
  unsigned short* K1 = (unsigned short*)(smem + 8192);
  unsigned short* V0 = (unsigned short*)(smem + 16384);
  unsigned short* V1 = (unsigned short*)(smem + 24576);

  const int tid = threadIdx.x;
  const int lane = tid & 63;
  const int wv = tid >> 6;
  const int q5 = lane & 31;   // this lane's q column
  const int hi = lane >> 5;   // k-half / key-half selector

  const int bh = blockIdx.x;  // all q-tiles of one (b,h) land on one XCD (stride-64 block IDs)
  const int qt = blockIdx.y;
  const int b = bh >> 4, h = bh & 15;

  const unsigned short* Qp = QK + (long)b * SS * NQK + h * DKH;
  const unsigned short* Kp = Qp + DM;
  const unsigned short* Vp = Vt + (long)h * DKH * MROWS + (long)b * SS;

  // Q (B-operand): col = q5, k = dstep*16 + hi*8 + i
  bf16x8 qf[4];
  {
    const unsigned short* qrow = Qp + (long)(qt * 128 + wv * 32 + q5) * NQK;
#pragma unroll
    for (int dstep = 0; dstep < 4; ++dstep)
      qf[dstep] = *reinterpret_cast<const bf16x8*>(qrow + dstep * 16 + hi * 8);
  }

  f32x16 accv[2];  // O^T: col q = q5, row d = dblk*32 + (r&3) + 8*(r>>2) + 4*hi
#pragma unroll
  for (int d = 0; d < 2; ++d)
#pragma unroll
    for (int r = 0; r < 16; ++r) accv[d][r] = 0.f;
  float m_run = -1e30f, l_run = 0.f;

  f32x16 zc;  // hoisted zero C-operand: fresh-dest QK MFMA, no per-tile acc init
#pragma unroll
  for (int r = 0; r < 16; ++r) zc[r] = 0.f;

  f32x16 s4A[2], s4B[2];

  auto stageK = [&](unsigned short* kd, int t) {
#pragma unroll
    for (int it = 0; it < 2; ++it) {
      const int u = it * 256 + tid;  // 16B-unit (dblk = u>>6, key = u&63)
      gload_lds16(Kp + (long)(t * 64 + (u & 63)) * NQK + (u >> 6) * 8, kd + u * 8);
    }
  };
  auto stageV = [&](unsigned short* vd, int t) {
#pragma unroll
    for (int it = 0; it < 2; ++it) {
      const int u = it * 256 + tid;  // 16B-unit (keyblk = u>>6, d = u&63)
      gload_lds16(Vp + (long)(u & 63) * MROWS + t * 64 + (u >> 6) * 8, vd + u * 8);
    }
  };

  // QK^T (swapped, 32x32x16): s4[kb] = S[key = kb*32 + rowmap][q5]
  auto QKf = [&](const unsigned short* K_, f32x16 (&s4)[2]) {
    __builtin_amdgcn_s_setprio(1);
#pragma unroll
    for (int kb = 0; kb < 2; ++kb)
#pragma unroll
      for (int dstep = 0; dstep < 4; ++dstep) {
        bf16x8 kf = *reinterpret_cast<const bf16x8*>(
            K_ + ((dstep * 2 + hi) * 64 + kb * 32 + q5) * 8);
        s4[kb] = __builtin_amdgcn_mfma_f32_32x32x16_bf16(kf, qf[dstep],
                                                         dstep ? s4[kb] : zc, 0, 0, 0);
      }
    __builtin_amdgcn_s_setprio(0);
  };

  // softmax (online, deferred-max) + PV for one tile's scores
  auto SMPV = [&](f32x16 (&s4)[2], const unsigned short* V_) {
    float t[16];
#pragma unroll
    for (int r = 0; r < 16; ++r) t[r] = fmaxf(s4[0][r], s4[1][r]);
#pragma unroll
    for (int w = 8; w >= 1; w >>= 1)
#pragma unroll
      for (int r = 0; r < w; ++r) t[r] = fmaxf(t[r], t[r + w]);
    const float mloc = fmaxf(t[0], __shfl_xor(t[0], 32));

    if (!__all(mloc <= m_run + 8.0f)) {   // defer-max (T13)
      const float mn = fmaxf(m_run, mloc);
      const float scl = __builtin_amdgcn_exp2f(m_run - mn);
      m_run = mn;
      l_run *= scl;
#pragma unroll
      for (int d = 0; d < 2; ++d)
#pragma unroll
        for (int r = 0; r < 16; ++r) accv[d][r] *= scl;
    }

#pragma unroll
    for (int kb = 0; kb < 2; ++kb)
#pragma unroll
      for (int r = 0; r < 16; ++r)
        s4[kb][r] = __builtin_amdgcn_exp2f(s4[kb][r] - m_run);
    float ts[16];
#pragma unroll
    for (int r = 0; r < 16; ++r) ts[r] = s4[0][r] + s4[1][r];
#pragma unroll
    for (int w = 8; w >= 1; w >>= 1)
#pragma unroll
      for (int r = 0; r < w; ++r) ts[r] += ts[r + w];
    l_run += ts[0] + __shfl_xor(ts[0], 32);

    // pack P->bf16 + cross-half exchange (2 shuffles/step) + PV
#pragma unroll
    for (int step = 0; step < 4; ++step) {
      const int kb = step >> 1, rb = (step & 1) * 8;
      const unsigned w0 = pack2(s4[kb][rb + 0], s4[kb][rb + 1]);
      const unsigned w1 = pack2(s4[kb][rb + 2], s4[kb][rb + 3]);
      const unsigned w2 = pack2(s4[kb][rb + 4], s4[kb][rb + 5]);
      const unsigned w3 = pack2(s4[kb][rb + 6], s4[kb][rb + 7]);
      const unsigned c = hi ? w0 : w2;          // lo lanes want partner w0; hi want partner w2
      const unsigned d = hi ? w1 : w3;
      const unsigned xc = (unsigned)__shfl_xor((int)c, 32);
      const unsigned xd = (unsigned)__shfl_xor((int)d, 32);
      union { unsigned u[4]; bf16x8 v; } pf;
      pf.u[0] = hi ? xc : w0;
      pf.u[1] = hi ? xd : w1;
      pf.u[2] = hi ? w2 : xc;
      pf.u[3] = hi ? w3 : xd;
      __builtin_amdgcn_s_setprio(1);
#pragma unroll
      for (int dblk = 0; dblk < 2; ++dblk) {
        bf16x8 vf = *reinterpret_cast<const bf16x8*>(
            V_ + ((step * 2 + hi) * 64 + dblk * 32 + q5) * 8);
        accv[dblk] = __builtin_amdgcn_mfma_f32_32x32x16_bf16(vf, pf.v, accv[dblk], 0, 0, 0);
      }
      __builtin_amdgcn_s_setprio(0);
    }
  };

  // ---- pipelined loop over NT = 32 KV tiles ----
  stageK(K0, 0);
  __syncthreads();

  // i = 0
  stageK(K1, 1);
  stageV(V0, 0);
  QKf(K0, s4A);
  __syncthreads();

#pragma unroll 1
  for (int p = 0; p < 15; ++p) {
    const int i = 1 + 2 * p;
    // odd i: QK(i) from K1, softmax+PV(i-1) from V0
    stageK(K0, i + 1);
    stageV(V1, i);
    QKf(K1, s4B);
    SMPV(s4A, V0);
    __syncthreads();
    // even i+1: QK(i+1) from K0, softmax+PV(i) from V1
    stageK(K1, i + 2);
    stageV(V0, i + 1);
    QKf(K0, s4A);
    SMPV(s4B, V1);
    __syncthreads();
  }

  // i = 31
  stageV(V1, 31);
  QKf(K1, s4B);
  SMPV(s4A, V0);   // tile 30
  __syncthreads();
  SMPV(s4B, V1);   // tile 31

  // ---- epilogue: normalize, store pairs (d even) as 4B words ----
  const float inv = 1.0f / l_run;
  const long row = (long)b * SS + qt * 128 + wv * 32 + q5;
  unsigned short* orow = AO + row * DM + h * DKH;
#pragma unroll
  for (int dblk = 0; dblk < 2; ++dblk)
#pragma unroll
    for (int j = 0; j < 8; ++j) {
      const int d0 = dblk * 32 + 8 * (j >> 1) + 4 * hi + 2 * (j & 1);
      const unsigned w = pack2(accv[dblk][2 * j] * inv, accv[dblk][2 * j + 1] * inv);
      *reinterpret_cast<unsigned*>(orow + d0) = w;
    }
}

// ---------------- launch ----------------

extern "C" void kernel_launch(void* const* d_in, const int* in_sizes, int n_in,
                              void* d_out, int out_size, void* d_ws, size_t ws_size,
                              hipStream_t stream) {
  const float* x  = (const float*)d_in[0];
  const float* Wq = (const float*)d_in[1];
  const float* bq = (const float*)d_in[2];
  const float* Wk = (const float*)d_in[3];
  const float* bk = (const float*)d_in[4];
  const float* Wv = (const float*)d_in[5];
  const float* bv = (const float*)d_in[6];
  const float* Wo = (const float*)d_in[7];
  const float* bo = (const float*)d_in[8];
  float* out = (float*)d_out;

  char* ws = (char*)d_ws;
  size_t off = 0;
  auto alloc = [&](size_t bytes) {
    void* p = ws + off;
    off += (bytes + 255) & ~(size_t)255;
    return p;
  };
  unsigned short* Xb   = (unsigned short*)alloc((size_t)MROWS * DM * 2);   // x bf16
  unsigned short* WTqk = (unsigned short*)alloc((size_t)2 * DM * DM * 2);  // WqT,WkT stacked [2048][1024]
  unsigned short* WTv  = (unsigned short*)alloc((size_t)DM * DM * 2);      // WvT [1024][1024]
  unsigned short* WTo  = (unsigned short*)alloc((size_t)DM * DM * 2);      // WoT [1024][1024]
  float*          bqk  = (float*)alloc((size_t)NQK * 4);
  unsigned short* QKb  = (unsigned short*)alloc((size_t)MROWS * NQK * 2);  // fused QK output
  unsigned short* Vtb  = (unsigned short*)alloc((size_t)DM * MROWS * 2);   // V^T [1024][8192]
  unsigned short* AOb  = (unsigned short*)alloc((size_t)MROWS * DM * 2);   // attention output

  cvt_bf16_kernel<<<(MROWS * DM / 4 + 255) / 256, 256, 0, stream>>>(x, Xb, MROWS * DM / 4);
  transpose_cvt_kernel<<<dim3(32, 32), 256, 0, stream>>>(Wq, WTqk);
  transpose_cvt_kernel<<<dim3(32, 32), 256, 0, stream>>>(Wk, WTqk + DM * DM);
  transpose_cvt_kernel<<<dim3(32, 32), 256, 0, stream>>>(Wv, WTv);
  transpose_cvt_kernel<<<dim3(32, 32), 256, 0, stream>>>(Wo, WTo);
  concat2_bias_kernel<<<(NQK + 255) / 256, 256, 0, stream>>>(bq, bk, bqk);

  // QK projection: [8192][2048] = Xb @ WTqk^T, Q columns pre-scaled by 0.125*log2(e)
  gemm_bt_kernel<unsigned short, true, false><<<dim3(MROWS / 128, NQK / 128), 256, 0, stream>>>(
      Xb, WTqk, bqk, QKb, MROWS, NQK, DM);
  // V^T directly: Vt[feature][token] = WTv @ Xb^T + bv (bias by row)
  gemm_bt_kernel<unsigned short, false, true><<<dim3(DM / 128, MROWS / 128), 256, 0, stream>>>(
      WTv, Xb, bv, Vtb, DM, MROWS, DM);

  attn_kernel<<<dim3(BB * NH, SS / 128), 256, 0, stream>>>(QKb, Vtb, AOb);

  // output projection -> fp32 d_out
  gemm_bt_kernel<float, false, false><<<dim3(MROWS / 128, DM / 128), 256, 0, stream>>>(
      AOb, WTo, bo, out, MROWS, DM, DM);
}